// Round 1
// baseline (686.790 us; speedup 1.0000x reference)
//
#include <hip/hip_runtime.h>

// y[b,o] = sum_i x[b,i]*W[i,o]*w_mask[b,i,o] + bias[o]*b_mask[b,o]
// B=32, IN_F=1024, OUT_F=4096. f32 tensors, int32 masks.
//
// Round-4 theory: harness poison is ~520 us fixed (2 GiB fills at 6.4 TB/s);
// kernel share ~160 us vs 90 us HBM floor => mask stream at ~3.3 TB/s only.
// VALU load is <15% of the HBM roofline; SQ_LDS_BANK_CONFLICT=0. Remaining
// suspect: latency-hiding. Old grid = 512 blocks = 2 blocks/CU = 2 waves/SIMD.
// This round: N_CHUNK 4->8 => 1024 blocks, 4 blocks/CU (launch_bounds(256,4)),
// doubling waves/SIMD to cover the vmcnt drain bubbles between unroll bodies.
// XCD locality kept: weight-slice sharers (vary b) have bid % 8 == chunk.

#define B_DIM 32
#define IN_F 1024
#define OUT_F 4096
#define N_CHUNK 8
#define I_CHUNK (IN_F / N_CHUNK)   // 128 i-rows per block
#define BO (B_DIM * OUT_F)         // 131072

typedef int   v4i __attribute__((ext_vector_type(4)));
typedef float v4f __attribute__((ext_vector_type(4)));

// partial[chunk][b][o] : 8 x 32 x 4096 f32 = 4 MiB in d_ws
__global__ __launch_bounds__(256, 4) void masked_gemv_partial(
    const float* __restrict__ x,       // [B, IN_F]
    const float* __restrict__ weight,  // [IN_F, OUT_F]
    const int* __restrict__ w_mask,    // [B, IN_F, OUT_F]
    float* __restrict__ partial)
{
    const int bid   = blockIdx.x;      // b*32 + o_blk*8 + chunk
    const int b     = bid >> 5;
    const int s     = bid & 31;
    const int o_blk = s >> 3;
    const int chunk = s & 7;
    const int i0    = chunk * I_CHUNK;
    const int o     = o_blk * 1024 + (threadIdx.x << 2);

    __shared__ float xs[I_CHUNK];      // 512 B
    if (threadIdx.x < I_CHUNK)
        xs[threadIdx.x] = x[b * IN_F + i0 + threadIdx.x];
    __syncthreads();

    const int*   mptr = w_mask + (size_t)b * IN_F * OUT_F + (size_t)i0 * OUT_F + o;
    const float* wptr = weight + (size_t)i0 * OUT_F + o;

    v4f acc = {0.f, 0.f, 0.f, 0.f};
#pragma unroll 8
    for (int i = 0; i < I_CHUNK; ++i) {
        const float xi = xs[i];  // wave-uniform -> LDS broadcast
        const v4i m = __builtin_nontemporal_load((const v4i*)(mptr + (size_t)i * OUT_F));
        const v4f w = *(const v4f*)(wptr + (size_t)i * OUT_F);
        acc.x = fmaf(xi * (float)m.x, w.x, acc.x);
        acc.y = fmaf(xi * (float)m.y, w.y, acc.y);
        acc.z = fmaf(xi * (float)m.z, w.z, acc.z);
        acc.w = fmaf(xi * (float)m.w, w.w, acc.w);
    }

    __builtin_nontemporal_store(acc,
        (v4f*)(partial + (size_t)chunk * BO + b * OUT_F + o));
}

__global__ __launch_bounds__(256) void reduce_bias_kernel(
    const float* __restrict__ partial,  // [N_CHUNK][B][OUT_F]
    const float* __restrict__ bias,     // [OUT_F]
    const int* __restrict__ b_mask,     // [B, OUT_F]
    float* __restrict__ out)            // [B, OUT_F]
{
    const int tid = blockIdx.x * 256 + threadIdx.x;  // [0, BO)
    float s0 = partial[tid]                  + partial[(size_t)1 * BO + tid];
    float s1 = partial[(size_t)2 * BO + tid] + partial[(size_t)3 * BO + tid];
    float s2 = partial[(size_t)4 * BO + tid] + partial[(size_t)5 * BO + tid];
    float s3 = partial[(size_t)6 * BO + tid] + partial[(size_t)7 * BO + tid];
    const int o = tid & (OUT_F - 1);
    out[tid] = fmaf(bias[o], (float)b_mask[tid], (s0 + s1) + (s2 + s3));
}

extern "C" void kernel_launch(void* const* d_in, const int* in_sizes, int n_in,
                              void* d_out, int out_size, void* d_ws, size_t ws_size,
                              hipStream_t stream) {
    const float* x      = (const float*)d_in[0];
    const float* weight = (const float*)d_in[1];
    const float* bias   = (const float*)d_in[2];
    const int*   w_mask = (const int*)d_in[3];
    const int*   b_mask = (const int*)d_in[4];
    float* out     = (float*)d_out;
    float* partial = (float*)d_ws;  // 4 MiB used

    masked_gemv_partial<<<B_DIM * 32, 256, 0, stream>>>(x, weight, w_mask, partial);
    reduce_bias_kernel<<<BO / 256, 256, 0, stream>>>(partial, bias, b_mask, out);
}

// Round 2
// 685.261 us; speedup vs baseline: 1.0022x; 1.0022x over previous
//
#include <hip/hip_runtime.h>

// y[b,o] = sum_i x[b,i]*W[i,o]*w_mask[b,i,o] + bias[o]*b_mask[b,o]
// B=32, IN_F=1024, OUT_F=4096. f32 tensors, int32 masks.
//
// Round-5 theory: round-4 (2->4 blocks/CU) was NEUTRAL => not latency-bound.
// Suspect per-CU L1/TA load-return ceiling: mask 16B + weight 16B per lane-iter
// = measured ~26 B/cyc/CU total load return, while HBM needs only ~10 B/cyc/CU.
// Fix: amortize weight over 8 batches per block (one weight load : 8 mask FMAs)
// => load-return per mask-byte drops 2x -> 1.125x, weight L2 traffic /8.
// Grid: 4 bgrp x 4 o_blk x 32 chunk = 512 blocks, 2/CU (launch_bounds(256,2)).
// Weight-slice sharers (vary bgrp) keep bid%8 = chunk%8 -> same XCD L2.

#define B_DIM 32
#define IN_F 1024
#define OUT_F 4096
#define BGRP 8                      // b-rows per block
#define NBG (B_DIM / BGRP)          // 4 b-groups
#define N_CHUNK 32
#define I_CHUNK (IN_F / N_CHUNK)    // 32 i-rows per block
#define BO (B_DIM * OUT_F)          // 131072

typedef int   v4i __attribute__((ext_vector_type(4)));
typedef float v4f __attribute__((ext_vector_type(4)));

// partial[chunk][b][o] : 32 x 32 x 4096 f32 = 16 MiB in d_ws
__global__ __launch_bounds__(256, 2) void masked_gemv_partial(
    const float* __restrict__ x,       // [B, IN_F]
    const float* __restrict__ weight,  // [IN_F, OUT_F]
    const int* __restrict__ w_mask,    // [B, IN_F, OUT_F]
    float* __restrict__ partial)
{
    const int bid   = blockIdx.x;         // bgrp*128 + o_blk*32 + chunk
    const int bgrp  = bid >> 7;           // 0..3
    const int o_blk = (bid >> 5) & 3;     // 0..3
    const int chunk = bid & 31;           // 0..31
    const int b0    = bgrp * BGRP;
    const int i0    = chunk * I_CHUNK;
    const int o     = o_blk * 1024 + (threadIdx.x << 2);

    // xs[bb][i] : 8 x 32 floats = 1 KiB
    __shared__ float xs[BGRP][I_CHUNK];
    {
        const int bb = threadIdx.x >> 5;   // 0..7
        const int ii = threadIdx.x & 31;   // 0..31
        xs[bb][ii] = x[(b0 + bb) * IN_F + i0 + ii];
    }
    __syncthreads();

    const float* wptr = weight + (size_t)i0 * OUT_F + o;
    const int*   mbase = w_mask + ((size_t)b0 * IN_F + i0) * OUT_F + o;

    v4f acc[BGRP];
#pragma unroll
    for (int bb = 0; bb < BGRP; ++bb) acc[bb] = (v4f){0.f, 0.f, 0.f, 0.f};

#pragma unroll 2
    for (int i = 0; i < I_CHUNK; ++i) {
        const v4f w = *(const v4f*)(wptr + (size_t)i * OUT_F);
#pragma unroll
        for (int bb = 0; bb < BGRP; ++bb) {
            const v4i m = __builtin_nontemporal_load(
                (const v4i*)(mbase + ((size_t)bb * IN_F + i) * OUT_F));
            const float xi = xs[bb][i];   // wave-uniform -> LDS broadcast
            acc[bb].x = fmaf(xi * (float)m.x, w.x, acc[bb].x);
            acc[bb].y = fmaf(xi * (float)m.y, w.y, acc[bb].y);
            acc[bb].z = fmaf(xi * (float)m.z, w.z, acc[bb].z);
            acc[bb].w = fmaf(xi * (float)m.w, w.w, acc[bb].w);
        }
    }

#pragma unroll
    for (int bb = 0; bb < BGRP; ++bb) {
        __builtin_nontemporal_store(acc[bb],
            (v4f*)(partial + (size_t)chunk * BO + (b0 + bb) * OUT_F + o));
    }
}

__global__ __launch_bounds__(256) void reduce_bias_kernel(
    const float* __restrict__ partial,  // [N_CHUNK][B][OUT_F]
    const float* __restrict__ bias,     // [OUT_F]
    const int* __restrict__ b_mask,     // [B, OUT_F]
    float* __restrict__ out)            // [B, OUT_F]
{
    const int tid = blockIdx.x * 256 + threadIdx.x;   // [0, BO/4)
    const v4f* p4 = (const v4f*)partial;
    v4f s = {0.f, 0.f, 0.f, 0.f};
#pragma unroll
    for (int c = 0; c < N_CHUNK; ++c) {
        const v4f v = p4[(size_t)c * (BO / 4) + tid];
        s.x += v.x; s.y += v.y; s.z += v.z; s.w += v.w;
    }
    const v4i bm = ((const v4i*)b_mask)[tid];
    const v4f bi = ((const v4f*)bias)[tid & (OUT_F / 4 - 1)];
    v4f r;
    r.x = fmaf(bi.x, (float)bm.x, s.x);
    r.y = fmaf(bi.y, (float)bm.y, s.y);
    r.z = fmaf(bi.z, (float)bm.z, s.z);
    r.w = fmaf(bi.w, (float)bm.w, s.w);
    ((v4f*)out)[tid] = r;
}

extern "C" void kernel_launch(void* const* d_in, const int* in_sizes, int n_in,
                              void* d_out, int out_size, void* d_ws, size_t ws_size,
                              hipStream_t stream) {
    const float* x      = (const float*)d_in[0];
    const float* weight = (const float*)d_in[1];
    const float* bias   = (const float*)d_in[2];
    const int*   w_mask = (const int*)d_in[3];
    const int*   b_mask = (const int*)d_in[4];
    float* out     = (float*)d_out;
    float* partial = (float*)d_ws;  // 16 MiB used

    masked_gemv_partial<<<NBG * 4 * N_CHUNK, 256, 0, stream>>>(x, weight, w_mask, partial);
    reduce_bias_kernel<<<BO / 4 / 256, 256, 0, stream>>>(partial, bias, b_mask, out);
}